// Round 8
// baseline (1583.707 us; speedup 1.0000x reference)
//
#include <hip/hip_runtime.h>

#define T_STEPS 2048
#define BATCH   128
#define HID     100     // LSTM hidden size
#define HP      112     // padded hidden length (multiple of 16)
#define NTH     448     // 7 waves of 64

// DPP quad_perm helpers (VALU pipe, immediate ctrl)
template <int CTRL>
__device__ __forceinline__ float dpp_mov(float v) {
    int y = __builtin_amdgcn_update_dpp(0, __float_as_int(v), CTRL, 0xF, 0xF, true);
    return __int_as_float(y);
}
template <int CTRL>
__device__ __forceinline__ float dpp_add(float v) {
    return v + dpp_mov<CTRL>(v);
}

__global__ __launch_bounds__(NTH)
__attribute__((amdgpu_waves_per_eu(2, 2)))
void lstm_caviar_kernel(
    const float* __restrict__ x,      // [T, B, 1]
    const float* __restrict__ W_ih,   // [400, 1]
    const float* __restrict__ W_hh,   // [400, 100]
    const float* __restrict__ b_ih,   // [400]
    const float* __restrict__ b_hh,   // [400]
    const float* __restrict__ W1,     // [64, 100]
    const float* __restrict__ b1,     // [64]
    const float* __restrict__ W2,     // [1, 64]
    const float* __restrict__ b2,     // [1]
    float* __restrict__ out)          // [1]
{
    __shared__ __align__(16) float h_buf[2][HP];
    __shared__ float x_lds[T_STEPS];
    __shared__ float red_lds[64];

    const int tid = threadIdx.x;
    const int j   = tid >> 2;     // hidden unit owned by this quad
    const int s   = tid & 3;      // k-split / gate-specialization lane
    const bool active = (j < HID);

    // stage batch-0 inputs (x[t,0,0] = flat[t*BATCH]) into LDS once
    for (int t = tid; t < T_STEPS; t += NTH)
        x_lds[t] = x[t * BATCH];
    if (tid < HP) { h_buf[0][tid] = 0.0f; h_buf[1][tid] = 0.0f; }

    // Preload W_hh fragments: lane covers k = 16*m + 4*s + d, m=0..6, d=0..3.
    // wi/bias pre-scaled by 0.25 so the 4-lane butterfly sums them to exactly 1x.
    float w[4][28];
    float wi4[4], bs4[4];
    #pragma unroll
    for (int g = 0; g < 4; ++g) {
        const int gate = g * HID + (active ? j : 0);
        const float* row = W_hh + gate * HID;
        #pragma unroll
        for (int m = 0; m < 7; ++m) {
            #pragma unroll
            for (int d = 0; d < 4; ++d) {
                const int k = 16 * m + 4 * s + d;
                w[g][m * 4 + d] = (active && k < HID) ? row[k] : 0.0f;
            }
        }
        wi4[g] = active ? 0.25f * W_ih[gate] : 0.0f;
        bs4[g] = active ? 0.25f * (b_ih[gate] + b_hh[gate]) : 0.0f;
    }

    const bool is_g = (s == 2);
    float c = 0.0f;
    __syncthreads();

    for (int t = 0; t < T_STEPS; ++t) {
        // Pin weights into AGPRs (loop-carried "+a" ties). CDNA VALU reads
        // AGPR sources directly, so FMAs consume them with zero move cost;
        // rematerialization from memory is impossible.
        #pragma unroll
        for (int g = 0; g < 4; ++g) {
            #pragma unroll
            for (int k = 0; k < 28; ++k)
                asm volatile("" : "+a"(w[g][k]));
            asm volatile("" : "+a"(wi4[g]), "+a"(bs4[g]));
        }

        const float* hb = h_buf[t & 1];
        const float xt = x_lds[t];

        float acc0 = fmaf(wi4[0], xt, bs4[0]);
        float acc1 = fmaf(wi4[1], xt, bs4[1]);
        float acc2 = fmaf(wi4[2], xt, bs4[2]);
        float acc3 = fmaf(wi4[3], xt, bs4[3]);

        #pragma unroll
        for (int m = 0; m < 7; ++m) {
            const float4 hv = *(const float4*)(hb + 16 * m + 4 * s);
            acc0 = fmaf(w[0][m*4+0], hv.x, acc0);
            acc0 = fmaf(w[0][m*4+1], hv.y, acc0);
            acc0 = fmaf(w[0][m*4+2], hv.z, acc0);
            acc0 = fmaf(w[0][m*4+3], hv.w, acc0);
            acc1 = fmaf(w[1][m*4+0], hv.x, acc1);
            acc1 = fmaf(w[1][m*4+1], hv.y, acc1);
            acc1 = fmaf(w[1][m*4+2], hv.z, acc1);
            acc1 = fmaf(w[1][m*4+3], hv.w, acc1);
            acc2 = fmaf(w[2][m*4+0], hv.x, acc2);
            acc2 = fmaf(w[2][m*4+1], hv.y, acc2);
            acc2 = fmaf(w[2][m*4+2], hv.z, acc2);
            acc2 = fmaf(w[2][m*4+3], hv.w, acc2);
            acc3 = fmaf(w[3][m*4+0], hv.x, acc3);
            acc3 = fmaf(w[3][m*4+1], hv.y, acc3);
            acc3 = fmaf(w[3][m*4+2], hv.z, acc3);
            acc3 = fmaf(w[3][m*4+3], hv.w, acc3);
        }

        // quad butterfly (VALU/DPP): every lane gets all four full gate sums
        acc0 = dpp_add<0xB1>(acc0); acc0 = dpp_add<0x4E>(acc0);
        acc1 = dpp_add<0xB1>(acc1); acc1 = dpp_add<0x4E>(acc1);
        acc2 = dpp_add<0xB1>(acc2); acc2 = dpp_add<0x4E>(acc2);
        acc3 = dpp_add<0xB1>(acc3); acc3 = dpp_add<0x4E>(acc3);

        // lane s activates gate s only (i,f,o: sigmoid; g: tanh = 2*sig(2x)-1)
        const float a  = (s & 1) ? ((s & 2) ? acc3 : acc1)
                                 : ((s & 2) ? acc2 : acc0);
        const float pre = is_g ? (a + a) : a;
        const float e   = __expf(-pre);
        const float v   = 1.0f / (1.0f + e);
        const float act = is_g ? (v + v - 1.0f) : v;

        // redistribute the four activations within the quad (DPP broadcasts)
        const float ig = dpp_mov<0x00>(act);
        const float fg = dpp_mov<0x55>(act);
        const float gg = dpp_mov<0xAA>(act);
        const float og = dpp_mov<0xFF>(act);

        c = fmaf(fg, c, ig * gg);
        const float e2 = __expf(-2.0f * c);
        const float th = 2.0f / (1.0f + e2) - 1.0f;
        const float h  = og * th;

        if (active && s == 0)
            h_buf[(t + 1) & 1][j] = h;
        __syncthreads();
    }

    // head: lin = W1 @ h + b1 (64), out = W2 @ lin + b2 (scalar)
    if (tid < 64) {
        const float* r = W1 + tid * HID;
        const float* hf = h_buf[0];   // T even -> final h in buf 0
        float a = 0.0f;
        for (int k = 0; k < HID; ++k)
            a = fmaf(r[k], hf[k], a);
        red_lds[tid] = a + b1[tid];
    }
    __syncthreads();
    if (tid == 0) {
        float a = b2[0];
        for (int k = 0; k < 64; ++k)
            a = fmaf(W2[k], red_lds[k], a);
        out[0] = a;
    }
}

extern "C" void kernel_launch(void* const* d_in, const int* in_sizes, int n_in,
                              void* d_out, int out_size, void* d_ws, size_t ws_size,
                              hipStream_t stream) {
    lstm_caviar_kernel<<<1, NTH, 0, stream>>>(
        (const float*)d_in[0],  // input_seq
        (const float*)d_in[1],  // W_ih
        (const float*)d_in[2],  // W_hh
        (const float*)d_in[3],  // b_ih
        (const float*)d_in[4],  // b_hh
        (const float*)d_in[5],  // W1
        (const float*)d_in[6],  // b1
        (const float*)d_in[7],  // W2
        (const float*)d_in[8],  // b2
        (float*)d_out);
}

// Round 9
// 1151.016 us; speedup vs baseline: 1.3759x; 1.3759x over previous
//
#include <hip/hip_runtime.h>

#define T_STEPS 2048
#define BATCH   128
#define HID     100     // LSTM hidden size
#define HP      112     // padded hidden length (multiple of 16)
#define NTH     448     // 7 waves of 64

// DPP quad_perm helpers (VALU pipe, immediate ctrl)
template <int CTRL>
__device__ __forceinline__ float dpp_mov(float v) {
    int y = __builtin_amdgcn_update_dpp(0, __float_as_int(v), CTRL, 0xF, 0xF, true);
    return __int_as_float(y);
}
template <int CTRL>
__device__ __forceinline__ float dpp_add(float v) {
    return v + dpp_mov<CTRL>(v);
}

__global__ __launch_bounds__(NTH)
__attribute__((amdgpu_waves_per_eu(1)))   // min-only: full 256-VGPR budget, no AGPR parking
void lstm_caviar_kernel(
    const float* __restrict__ x,      // [T, B, 1]
    const float* __restrict__ W_ih,   // [400, 1]
    const float* __restrict__ W_hh,   // [400, 100]
    const float* __restrict__ b_ih,   // [400]
    const float* __restrict__ b_hh,   // [400]
    const float* __restrict__ W1,     // [64, 100]
    const float* __restrict__ b1,     // [64]
    const float* __restrict__ W2,     // [1, 64]
    const float* __restrict__ b2,     // [1]
    float* __restrict__ out)          // [1]
{
    __shared__ __align__(16) float h_buf[2][HP];
    __shared__ float x_lds[T_STEPS];
    __shared__ float red_lds[64];

    const int tid = threadIdx.x;
    const int j   = tid >> 2;     // hidden unit owned by this quad
    const int s   = tid & 3;      // k-split / gate-specialization lane
    const bool active = (j < HID);

    // stage batch-0 inputs (x[t,0,0] = flat[t*BATCH]) into LDS once
    for (int t = tid; t < T_STEPS; t += NTH)
        x_lds[t] = x[t * BATCH];
    if (tid < HP) { h_buf[0][tid] = 0.0f; h_buf[1][tid] = 0.0f; }

    // Preload W_hh fragments: lane covers k = 16*m + 4*s + d, m=0..6, d=0..3.
    // wi/bias pre-scaled by 0.25 so the 4-lane butterfly sums them to exactly 1x.
    float w[4][28];
    float wi4[4], bs4[4];
    #pragma unroll
    for (int g = 0; g < 4; ++g) {
        const int gate = g * HID + (active ? j : 0);
        const float* row = W_hh + gate * HID;
        #pragma unroll
        for (int m = 0; m < 7; ++m) {
            #pragma unroll
            for (int d = 0; d < 4; ++d) {
                const int k = 16 * m + 4 * s + d;
                w[g][m * 4 + d] = (active && k < HID) ? row[k] : 0.0f;
            }
        }
        wi4[g] = active ? 0.25f * W_ih[gate] : 0.0f;
        bs4[g] = active ? 0.25f * (b_ih[gate] + b_hh[gate]) : 0.0f;
    }

    const bool is_g = (s == 2);
    float c = 0.0f;
    __syncthreads();

    for (int t = 0; t < T_STEPS; ++t) {
        // Pin weights into arch VGPRs (loop-carried "+v" ties; zero instrs when
        // already resident). With the relaxed budget there is no pressure to
        // park them in AGPRs, so these should now be free.
        #pragma unroll
        for (int g = 0; g < 4; ++g) {
            #pragma unroll
            for (int k = 0; k < 28; ++k)
                asm volatile("" : "+v"(w[g][k]));
            asm volatile("" : "+v"(wi4[g]), "+v"(bs4[g]));
        }

        const float* hb = h_buf[t & 1];
        const float xt = x_lds[t];

        float acc0 = fmaf(wi4[0], xt, bs4[0]);
        float acc1 = fmaf(wi4[1], xt, bs4[1]);
        float acc2 = fmaf(wi4[2], xt, bs4[2]);
        float acc3 = fmaf(wi4[3], xt, bs4[3]);

        #pragma unroll
        for (int m = 0; m < 7; ++m) {
            const float4 hv = *(const float4*)(hb + 16 * m + 4 * s);
            acc0 = fmaf(w[0][m*4+0], hv.x, acc0);
            acc0 = fmaf(w[0][m*4+1], hv.y, acc0);
            acc0 = fmaf(w[0][m*4+2], hv.z, acc0);
            acc0 = fmaf(w[0][m*4+3], hv.w, acc0);
            acc1 = fmaf(w[1][m*4+0], hv.x, acc1);
            acc1 = fmaf(w[1][m*4+1], hv.y, acc1);
            acc1 = fmaf(w[1][m*4+2], hv.z, acc1);
            acc1 = fmaf(w[1][m*4+3], hv.w, acc1);
            acc2 = fmaf(w[2][m*4+0], hv.x, acc2);
            acc2 = fmaf(w[2][m*4+1], hv.y, acc2);
            acc2 = fmaf(w[2][m*4+2], hv.z, acc2);
            acc2 = fmaf(w[2][m*4+3], hv.w, acc2);
            acc3 = fmaf(w[3][m*4+0], hv.x, acc3);
            acc3 = fmaf(w[3][m*4+1], hv.y, acc3);
            acc3 = fmaf(w[3][m*4+2], hv.z, acc3);
            acc3 = fmaf(w[3][m*4+3], hv.w, acc3);
        }

        // quad butterfly (VALU/DPP): every lane gets all four full gate sums
        acc0 = dpp_add<0xB1>(acc0); acc0 = dpp_add<0x4E>(acc0);
        acc1 = dpp_add<0xB1>(acc1); acc1 = dpp_add<0x4E>(acc1);
        acc2 = dpp_add<0xB1>(acc2); acc2 = dpp_add<0x4E>(acc2);
        acc3 = dpp_add<0xB1>(acc3); acc3 = dpp_add<0x4E>(acc3);

        // lane s activates gate s only (i,f,o: sigmoid; g: tanh = 2*sig(2x)-1)
        const float a  = (s & 1) ? ((s & 2) ? acc3 : acc1)
                                 : ((s & 2) ? acc2 : acc0);
        const float pre = is_g ? (a + a) : a;
        const float e   = __expf(-pre);
        const float v   = 1.0f / (1.0f + e);
        const float act = is_g ? (v + v - 1.0f) : v;

        // redistribute the four activations within the quad (DPP broadcasts)
        const float ig = dpp_mov<0x00>(act);
        const float fg = dpp_mov<0x55>(act);
        const float gg = dpp_mov<0xAA>(act);
        const float og = dpp_mov<0xFF>(act);

        c = fmaf(fg, c, ig * gg);
        const float e2 = __expf(-2.0f * c);
        const float th = 2.0f / (1.0f + e2) - 1.0f;
        const float h  = og * th;

        if (active && s == 0)
            h_buf[(t + 1) & 1][j] = h;
        __syncthreads();
    }

    // head: lin = W1 @ h + b1 (64), out = W2 @ lin + b2 (scalar)
    if (tid < 64) {
        const float* r = W1 + tid * HID;
        const float* hf = h_buf[0];   // T even -> final h in buf 0
        float a = 0.0f;
        for (int k = 0; k < HID; ++k)
            a = fmaf(r[k], hf[k], a);
        red_lds[tid] = a + b1[tid];
    }
    __syncthreads();
    if (tid == 0) {
        float a = b2[0];
        for (int k = 0; k < 64; ++k)
            a = fmaf(W2[k], red_lds[k], a);
        out[0] = a;
    }
}

extern "C" void kernel_launch(void* const* d_in, const int* in_sizes, int n_in,
                              void* d_out, int out_size, void* d_ws, size_t ws_size,
                              hipStream_t stream) {
    lstm_caviar_kernel<<<1, NTH, 0, stream>>>(
        (const float*)d_in[0],  // input_seq
        (const float*)d_in[1],  // W_ih
        (const float*)d_in[2],  // W_hh
        (const float*)d_in[3],  // b_ih
        (const float*)d_in[4],  // b_hh
        (const float*)d_in[5],  // W1
        (const float*)d_in[6],  // b1
        (const float*)d_in[7],  // W2
        (const float*)d_in[8],  // b2
        (float*)d_out);
}